// Round 13
// baseline (135.165 us; speedup 1.0000x reference)
//
#include <hip/hip_runtime.h>
#include <math.h>

#define D 100
#define NEG_SLOPE 0.2f
#define CHUNK 16
#define ROWU 52          // uints per packed-f16 row, padded 50->52 for 16B align

typedef _Float16 f16x2 __attribute__((ext_vector_type(2)));
union U32H2 { unsigned int u; f16x2 h; };

__device__ __forceinline__ unsigned int pkh2(float x, float y) {
    U32H2 c; c.h.x = (_Float16)x; c.h.y = (_Float16)y; return c.u;
}
__device__ __forceinline__ float f16lo(unsigned int u) { U32H2 c; c.u = u; return (float)c.h.x; }
__device__ __forceinline__ float f16hi(unsigned int u) { U32H2 c; c.u = u; return (float)c.h.y; }

// 2-wide f16 dot + fp32 accumulate: v_dot2_f32_f16 (1 VALU inst vs 4)
__device__ __forceinline__ float dot2u(unsigned int au, unsigned int xu, float acc) {
#if __has_builtin(__builtin_amdgcn_fdot2)
    U32H2 a, x; a.u = au; x.u = xu;
    return __builtin_amdgcn_fdot2(a.h, x.h, acc, false);
#else
    return acc + f16lo(au) * f16lo(xu) + f16hi(au) * f16hi(xu);
#endif
}

// Pair-parallel boundary scatter: row_ptr[v] = first pair index with seg >= v.
__global__ void build_row_ptr(const int* __restrict__ seg,
                              int* __restrict__ row_ptr,
                              int n, int P)
{
    int p = blockIdx.x * blockDim.x + threadIdx.x;
    if (p >= P) return;
    int s0 = seg[p];
    if (p == 0)
        for (int v = 0; v <= s0; v++) row_ptr[v] = 0;
    int s1 = (p + 1 < P) ? seg[p + 1] : n;
    for (int v = s0 + 1; v <= s1; v++) row_ptr[v] = p + 1;
}

// hidden (fp32, rows of 100) -> packed f16 rows of ROWU uints (padded).
__global__ void cvt_hidden(const float* __restrict__ hidden,
                           unsigned int* __restrict__ hb, int total /* n*25 */)
{
    int t = blockIdx.x * blockDim.x + threadIdx.x;
    if (t >= total) return;
    int node = t / 25, k = t - node * 25;       // 25 float4-groups per row
    float4 f = ((const float4*)hidden)[node * 25 + k];
    *(uint2*)&hb[node * ROWU + 2 * k] = make_uint2(pkh2(f.x, f.y), pkh2(f.z, f.w));
}

// One wave per node. CHUNK=16, 4 lanes/pair, f16 gathers + v_dot2_f32_f16.
// R13: hw hoisted to registers (R12 re-read it from LDS every chunk) and
// 1-deep cross-chunk gather prefetch — chunk c+1's nbr+row loads issue at the
// top of chunk c and fly behind softmax + phase B (most nodes = 2 chunks).
__launch_bounds__(256, 7)   // 28 waves/CU; VGPR cap 73 (live set ~60)
__global__ void gat_agg_kernel(const float* __restrict__ hidden,
                               const float* __restrict__ W,
                               const int* __restrict__ nbr,
                               const int* __restrict__ row_ptr,
                               const unsigned int* __restrict__ hb,
                               float* __restrict__ out,
                               int n)
{
    __shared__ __align__(16) unsigned int s_hwp[4][ROWU];         // 0.83 KB
    __shared__ __align__(16) unsigned int s_rows[4][CHUNK][ROWU]; // 13.3 KB
    __shared__ __align__(16) float        s_e[4][CHUNK];          // 0.25 KB

    const int lane = threadIdx.x & 63;
    const int wid  = threadIdx.x >> 6;
    const int v    = blockIdx.x * 4 + wid;
    if (v >= n) return;          // wave-uniform exit; no block barriers used

    // hw[d] = hidden[v][d] * W[d] (fp32 product, f16-packed into LDS)
    if (lane < 50) {
        float2 h2 = ((const float2*)(hidden + (long)v * D))[lane];
        float2 w2 = ((const float2*)W)[lane];
        s_hwp[wid][lane] = pkh2(h2.x * w2.x, h2.y * w2.y);
    }
    __threadfence_block();

    const int start = row_ptr[v];
    const int end   = row_ptr[v + 1];

    if (end <= start) {          // empty segment: zeros (matches reference)
        if (lane < D / 2)
            ((float2*)(out + (long)v * D))[lane] = make_float2(0.f, 0.f);
        return;
    }

    const int q  = lane >> 4;    // quarter 0..3: uint4s q*3..q*3+2 (+tail on q0)
    const int jl = lane & 15;    // pair slot within the 16-chunk
    const int t0 = q * 3;

    // hoist hw fragment into registers (loop-invariant; 14 regs)
    const uint4* hwq = ((const uint4*)&s_hwp[wid][0]) + t0;
    const uint4 a0 = hwq[0], a1 = hwq[1], a2 = hwq[2];
    uint2 at = make_uint2(0u, 0u);
    if (q == 0) at = *(const uint2*)&s_hwp[wid][48];

    // prefetch chunk 0's gathers
    bool pv = jl < min(CHUNK, end - start);
    {
        const int nbv = pv ? nbr[start + jl] : 0;
        // fallthrough loads below
        const uint4* r16 = ((const uint4*)hb) + nbv * (ROWU / 4) + t0;
        // declared after; see x0.. below
        // (kept in this scope via assignment)
        // -- actual declarations:
        // handled right after this block
        (void)r16;
    }
    // (re-do cleanly: first-chunk prefetch)
    uint4 x0, x1, x2;
    uint2 xt = make_uint2(0u, 0u);
    {
        const int nbv = pv ? nbr[start + jl] : 0;
        const uint4* r16 = ((const uint4*)hb) + nbv * (ROWU / 4) + t0;
        x0 = r16[0]; x1 = r16[1]; x2 = r16[2];
        if (q == 0) xt = *(const uint2*)&hb[nbv * ROWU + 48];
    }

    float m = -INFINITY, z = 0.f;
    float accx = 0.f, accy = 0.f;

    for (int c = start; c < end; c += CHUNK) {
        const int  cnt = min(CHUNK, end - c);
        const bool pvc = jl < cnt;

        // ---- prefetch chunk c+1 (wave-uniform guard; loads fly over phase B)
        const int cn = c + CHUNK;
        const bool havenext = cn < end;
        uint4 y0, y1, y2;
        uint2 yt = make_uint2(0u, 0u);
        if (havenext) {
            const bool pvn  = jl < min(CHUNK, end - cn);
            const int  nbvn = pvn ? nbr[cn + jl] : 0;
            const uint4* rn = ((const uint4*)hb) + nbvn * (ROWU / 4) + t0;
            y0 = rn[0]; y1 = rn[1]; y2 = rn[2];
            if (q == 0) yt = *(const uint2*)&hb[nbvn * ROWU + 48];
        }

        // ---- Phase A: fdot2 on current regs ----
        float p0 = 0.f, p1 = 0.f, p2 = 0.f, p3 = 0.f;
        p0 = dot2u(a0.x, x0.x, p0);  p1 = dot2u(a0.y, x0.y, p1);
        p2 = dot2u(a0.z, x0.z, p2);  p3 = dot2u(a0.w, x0.w, p3);
        p0 = dot2u(a1.x, x1.x, p0);  p1 = dot2u(a1.y, x1.y, p1);
        p2 = dot2u(a1.z, x1.z, p2);  p3 = dot2u(a1.w, x1.w, p3);
        p0 = dot2u(a2.x, x2.x, p0);  p1 = dot2u(a2.y, x2.y, p1);
        p2 = dot2u(a2.z, x2.z, p2);  p3 = dot2u(a2.w, x2.w, p3);
        if (q == 0) {
            p0 = dot2u(at.x, xt.x, p0);
            p1 = dot2u(at.y, xt.y, p1);
        }

        // stage raw f16 row to LDS (16B-aligned: ROWU*4 = 208 = 13*16)
        uint4* dst16 = ((uint4*)&s_rows[wid][jl][0]) + t0;
        dst16[0] = x0; dst16[1] = x1; dst16[2] = x2;
        if (q == 0) *(uint2*)&s_rows[wid][jl][48] = xt;

        float part = (p0 + p1) + (p2 + p3);
        part += __shfl_xor(part, 16, 64);    // combine quarters
        part += __shfl_xor(part, 32, 64);
        const float s = pvc ? (part >= 0.f ? part : NEG_SLOPE * part)
                            : -INFINITY;

        // ---- online softmax: s duplicated across quarters -> 4-step reductions
        float mx = s;
        #pragma unroll
        for (int off = 8; off >= 1; off >>= 1)
            mx = fmaxf(mx, __shfl_xor(mx, off, 64));
        const float m_new = fmaxf(m, mx);
        const float scale = __expf(m - m_new);         // first chunk: 0
        const float e     = pvc ? __expf(s - m_new) : 0.f;
        float es = e;
        #pragma unroll
        for (int off = 8; off >= 1; off >>= 1)
            es += __shfl_xor(es, off, 64);             // sum within 16-group
        z = z * scale + es;
        accx *= scale; accy *= scale;

        if (lane < CHUNK) s_e[wid][lane] = e;          // q0 lanes: jl == lane
        __threadfence_block();                         // LDS stores -> reads

        // ---- Phase B: lane-per-dim accumulate from f16 LDS ----
        const int cnt4 = (cnt + 3) & ~3;               // <= 16
        if (lane < D / 2) {
            for (int j0 = 0; j0 < cnt4; j0 += 4) {
                const float4 ev = *(const float4*)&s_e[wid][j0];  // broadcast
                const unsigned int u0 = s_rows[wid][j0    ][lane];
                const unsigned int u1 = s_rows[wid][j0 + 1][lane];
                const unsigned int u2 = s_rows[wid][j0 + 2][lane];
                const unsigned int u3 = s_rows[wid][j0 + 3][lane];
                accx += ev.x * f16lo(u0);  accy += ev.x * f16hi(u0);
                accx += ev.y * f16lo(u1);  accy += ev.y * f16hi(u1);
                accx += ev.z * f16lo(u2);  accy += ev.z * f16hi(u2);
                accx += ev.w * f16lo(u3);  accy += ev.w * f16hi(u3);
            }
        }
        __threadfence_block();   // phase-B reads done before next chunk's stores
        m = m_new;

        // ---- rotate prefetched regs into place ----
        if (havenext) { x0 = y0; x1 = y1; x2 = y2; xt = yt; }
    }

    if (lane < D / 2) {
        const float inv = 1.f / z;
        ((float2*)(out + (long)v * D))[lane] = make_float2(accx * inv, accy * inv);
    }
}

extern "C" void kernel_launch(void* const* d_in, const int* in_sizes, int n_in,
                              void* d_out, int out_size, void* d_ws, size_t ws_size,
                              hipStream_t stream) {
    const float* hidden = (const float*)d_in[0];
    const float* W      = (const float*)d_in[1];
    const int*   seg    = (const int*)d_in[2];
    const int*   nbr    = (const int*)d_in[3];
    float*       out    = (float*)d_out;

    const int Ddim = in_sizes[1];           // 100
    const int n    = in_sizes[0] / Ddim;    // 50000
    const int P    = in_sizes[2];           // ~1.3M pairs

    // ws layout: row_ptr (n+1 ints) | hb (n*ROWU uints, 256B-aligned)
    int* row_ptr = (int*)d_ws;
    size_t hb_off = (((size_t)(n + 1) * 4) + 255) & ~(size_t)255;
    unsigned int* hb = (unsigned int*)((char*)d_ws + hb_off);

    hipLaunchKernelGGL(build_row_ptr, dim3((P + 255) / 256), dim3(256), 0, stream,
                       seg, row_ptr, n, P);
    const int total = n * 25;               // float4-groups in hidden
    hipLaunchKernelGGL(cvt_hidden, dim3((total + 255) / 256), dim3(256), 0, stream,
                       hidden, hb, total);
    hipLaunchKernelGGL(gat_agg_kernel, dim3((n + 3) / 4), dim3(256), 0, stream,
                       hidden, W, nbr, row_ptr, hb, out, n);
}

// Round 14
// 130.452 us; speedup vs baseline: 1.0361x; 1.0361x over previous
//
#include <hip/hip_runtime.h>
#include <math.h>

#define D 100
#define NEG_SLOPE 0.2f
#define CHUNK 16
#define ROWU 52          // uints per packed-f16 row, padded 50->52 for 16B align

typedef _Float16 f16x2 __attribute__((ext_vector_type(2)));
union U32H2 { unsigned int u; f16x2 h; };

__device__ __forceinline__ unsigned int pkh2(float x, float y) {
    U32H2 c; c.h.x = (_Float16)x; c.h.y = (_Float16)y; return c.u;
}
__device__ __forceinline__ float f16lo(unsigned int u) { U32H2 c; c.u = u; return (float)c.h.x; }
__device__ __forceinline__ float f16hi(unsigned int u) { U32H2 c; c.u = u; return (float)c.h.y; }

// 2-wide f16 dot + fp32 accumulate: v_dot2_f32_f16
__device__ __forceinline__ float dot2u(unsigned int au, unsigned int xu, float acc) {
#if __has_builtin(__builtin_amdgcn_fdot2)
    U32H2 a, x; a.u = au; x.u = xu;
    return __builtin_amdgcn_fdot2(a.h, x.h, acc, false);
#else
    return acc + f16lo(au) * f16lo(xu) + f16hi(au) * f16hi(xu);
#endif
}

// DPP cross-lane (VALU pipe, ~4-8cy vs ds_swizzle ~30-60cy).
// quad_perm xor1=0xB1, xor2=0x4E; row_ror:4=0x124, row_ror:8=0x128.
template<int CTRL>
__device__ __forceinline__ float dppf(float x) {
    return __uint_as_float((unsigned)__builtin_amdgcn_update_dpp(
        0, (int)__float_as_uint(x), CTRL, 0xF, 0xF, true));
}
// full reduction within each 16-lane group (after quads uniform, ror4/ror8
// fold the 4 quads -> every lane holds the group result)
__device__ __forceinline__ float red16_max(float x) {
    x = fmaxf(x, dppf<0xB1>(x));
    x = fmaxf(x, dppf<0x4E>(x));
    x = fmaxf(x, dppf<0x124>(x));
    x = fmaxf(x, dppf<0x128>(x));
    return x;
}
__device__ __forceinline__ float red16_sum(float x) {
    x += dppf<0xB1>(x);
    x += dppf<0x4E>(x);
    x += dppf<0x124>(x);
    x += dppf<0x128>(x);
    return x;
}

// Pair-parallel boundary scatter: row_ptr[v] = first pair index with seg >= v.
__global__ void build_row_ptr(const int* __restrict__ seg,
                              int* __restrict__ row_ptr,
                              int n, int P)
{
    int p = blockIdx.x * blockDim.x + threadIdx.x;
    if (p >= P) return;
    int s0 = seg[p];
    if (p == 0)
        for (int v = 0; v <= s0; v++) row_ptr[v] = 0;
    int s1 = (p + 1 < P) ? seg[p + 1] : n;
    for (int v = s0 + 1; v <= s1; v++) row_ptr[v] = p + 1;
}

// hidden (fp32, rows of 100) -> packed f16 rows of ROWU uints (padded).
__global__ void cvt_hidden(const float* __restrict__ hidden,
                           unsigned int* __restrict__ hb, int total /* n*25 */)
{
    int t = blockIdx.x * blockDim.x + threadIdx.x;
    if (t >= total) return;
    int node = t / 25, k = t - node * 25;       // 25 float4-groups per row
    float4 f = ((const float4*)hidden)[node * 25 + k];
    *(uint2*)&hb[node * ROWU + 2 * k] = make_uint2(pkh2(f.x, f.y), pkh2(f.z, f.w));
}

// One wave per node. CHUNK=16, 4 lanes/pair, f16 gathers + v_dot2_f32_f16.
// R14: softmax reduction trees moved from ds_swizzle (LDS pipe, serial
// ~30-60cy/step) to DPP (VALU pipe) — only the 2 cross-quarter combines
// remain on the LDS pipe. hw kept in registers. No cross-chunk prefetch
// (R13 showed it costs more VALU than the latency it hides).
__launch_bounds__(256, 7)   // 28 waves/CU; VGPR cap 73
__global__ void gat_agg_kernel(const float* __restrict__ hidden,
                               const float* __restrict__ W,
                               const int* __restrict__ nbr,
                               const int* __restrict__ row_ptr,
                               const unsigned int* __restrict__ hb,
                               float* __restrict__ out,
                               int n)
{
    __shared__ __align__(16) unsigned int s_hwp[4][ROWU];         // 0.83 KB
    __shared__ __align__(16) unsigned int s_rows[4][CHUNK][ROWU]; // 13.3 KB
    __shared__ __align__(16) float        s_e[4][CHUNK];          // 0.25 KB

    const int lane = threadIdx.x & 63;
    const int wid  = threadIdx.x >> 6;
    const int v    = blockIdx.x * 4 + wid;
    if (v >= n) return;          // wave-uniform exit; no block barriers used

    // hw[d] = hidden[v][d] * W[d] (fp32 product, f16-packed into LDS)
    if (lane < 50) {
        float2 h2 = ((const float2*)(hidden + (long)v * D))[lane];
        float2 w2 = ((const float2*)W)[lane];
        s_hwp[wid][lane] = pkh2(h2.x * w2.x, h2.y * w2.y);
    }
    __threadfence_block();

    const int start = row_ptr[v];
    const int end   = row_ptr[v + 1];

    if (end <= start) {          // empty segment: zeros (matches reference)
        if (lane < D / 2)
            ((float2*)(out + (long)v * D))[lane] = make_float2(0.f, 0.f);
        return;
    }

    const int q  = lane >> 4;    // quarter 0..3: uint4s q*3..q*3+2 (+tail on q0)
    const int jl = lane & 15;    // pair slot within the 16-chunk
    const int t0 = q * 3;

    // hoist hw fragment into registers (loop-invariant; 14 regs)
    const uint4* hwq = ((const uint4*)&s_hwp[wid][0]) + t0;
    const uint4 a0 = hwq[0], a1 = hwq[1], a2 = hwq[2];
    uint2 at = make_uint2(0u, 0u);
    if (q == 0) at = *(const uint2*)&s_hwp[wid][48];

    float m = -INFINITY, z = 0.f;
    float accx = 0.f, accy = 0.f;

    for (int c = start; c < end; c += CHUNK) {
        const int  cnt = min(CHUNK, end - c);
        const bool pv  = jl < cnt;

        // invalid lanes gather row 0 (finite, in-bounds); e=0 masks it later
        const int nbv = pv ? nbr[c + jl] : 0;
        const uint4* row16 = ((const uint4*)hb) + nbv * (ROWU / 4) + t0;

        // ---- Phase A: f16 quarter-row gather (3x16B + 8B tail), fdot2 ----
        uint4 x0 = row16[0], x1 = row16[1], x2 = row16[2];
        uint2 xt = make_uint2(0u, 0u);
        if (q == 0) xt = *(const uint2*)&hb[nbv * ROWU + 48];   // dims 96..99

        float p0 = 0.f, p1 = 0.f, p2 = 0.f, p3 = 0.f;
        p0 = dot2u(a0.x, x0.x, p0);  p1 = dot2u(a0.y, x0.y, p1);
        p2 = dot2u(a0.z, x0.z, p2);  p3 = dot2u(a0.w, x0.w, p3);
        p0 = dot2u(a1.x, x1.x, p0);  p1 = dot2u(a1.y, x1.y, p1);
        p2 = dot2u(a1.z, x1.z, p2);  p3 = dot2u(a1.w, x1.w, p3);
        p0 = dot2u(a2.x, x2.x, p0);  p1 = dot2u(a2.y, x2.y, p1);
        p2 = dot2u(a2.z, x2.z, p2);  p3 = dot2u(a2.w, x2.w, p3);
        if (q == 0) {
            p0 = dot2u(at.x, xt.x, p0);
            p1 = dot2u(at.y, xt.y, p1);
        }

        // stage raw f16 row to LDS (16B-aligned: ROWU*4 = 208 = 13*16)
        uint4* dst16 = ((uint4*)&s_rows[wid][jl][0]) + t0;
        dst16[0] = x0; dst16[1] = x1; dst16[2] = x2;
        if (q == 0) *(uint2*)&s_rows[wid][jl][48] = xt;

        float part = (p0 + p1) + (p2 + p3);
        part += __shfl_xor(part, 16, 64);    // combine quarters (LDS pipe)
        part += __shfl_xor(part, 32, 64);
        const float s = pv ? (part >= 0.f ? part : NEG_SLOPE * part)
                           : -INFINITY;

        // ---- online softmax: DPP trees within each 16-group ----
        const float m_new = fmaxf(m, red16_max(s));
        const float scale = __expf(m - m_new);         // first chunk: 0
        const float e     = pv ? __expf(s - m_new) : 0.f;
        z = z * scale + red16_sum(e);
        accx *= scale; accy *= scale;

        if (lane < CHUNK) s_e[wid][lane] = e;          // q0 lanes: jl == lane
        __threadfence_block();                         // LDS stores -> reads

        // ---- Phase B: lane-per-dim accumulate from f16 LDS ----
        const int cnt4 = (cnt + 3) & ~3;               // <= 16
        if (lane < D / 2) {
            for (int j0 = 0; j0 < cnt4; j0 += 4) {
                const float4 ev = *(const float4*)&s_e[wid][j0];  // broadcast
                const unsigned int u0 = s_rows[wid][j0    ][lane];
                const unsigned int u1 = s_rows[wid][j0 + 1][lane];
                const unsigned int u2 = s_rows[wid][j0 + 2][lane];
                const unsigned int u3 = s_rows[wid][j0 + 3][lane];
                accx += ev.x * f16lo(u0);  accy += ev.x * f16hi(u0);
                accx += ev.y * f16lo(u1);  accy += ev.y * f16hi(u1);
                accx += ev.z * f16lo(u2);  accy += ev.z * f16hi(u2);
                accx += ev.w * f16lo(u3);  accy += ev.w * f16hi(u3);
            }
        }
        __threadfence_block();   // phase-B reads done before next chunk's stores
        m = m_new;
    }

    if (lane < D / 2) {
        const float inv = 1.f / z;
        ((float2*)(out + (long)v * D))[lane] = make_float2(accx * inv, accy * inv);
    }
}

extern "C" void kernel_launch(void* const* d_in, const int* in_sizes, int n_in,
                              void* d_out, int out_size, void* d_ws, size_t ws_size,
                              hipStream_t stream) {
    const float* hidden = (const float*)d_in[0];
    const float* W      = (const float*)d_in[1];
    const int*   seg    = (const int*)d_in[2];
    const int*   nbr    = (const int*)d_in[3];
    float*       out    = (float*)d_out;

    const int Ddim = in_sizes[1];           // 100
    const int n    = in_sizes[0] / Ddim;    // 50000
    const int P    = in_sizes[2];           // ~1.3M pairs

    // ws layout: row_ptr (n+1 ints) | hb (n*ROWU uints, 256B-aligned)
    int* row_ptr = (int*)d_ws;
    size_t hb_off = (((size_t)(n + 1) * 4) + 255) & ~(size_t)255;
    unsigned int* hb = (unsigned int*)((char*)d_ws + hb_off);

    hipLaunchKernelGGL(build_row_ptr, dim3((P + 255) / 256), dim3(256), 0, stream,
                       seg, row_ptr, n, P);
    const int total = n * 25;               // float4-groups in hidden
    hipLaunchKernelGGL(cvt_hidden, dim3((total + 255) / 256), dim3(256), 0, stream,
                       hidden, hb, total);
    hipLaunchKernelGGL(gat_agg_kernel, dim3((n + 3) / 4), dim3(256), 0, stream,
                       hidden, W, nbr, row_ptr, hb, out, n);
}

// Round 15
// 128.806 us; speedup vs baseline: 1.0494x; 1.0128x over previous
//
#include <hip/hip_runtime.h>
#include <math.h>

#define D 100
#define NEG_SLOPE 0.2f
#define CHUNK 16
#define ROWU 52          // uints per packed-f16 row, padded 50->52 for 16B align

typedef _Float16 f16x2 __attribute__((ext_vector_type(2)));
union U32H2 { unsigned int u; f16x2 h; };

__device__ __forceinline__ unsigned int pkh2(float x, float y) {
    U32H2 c; c.h.x = (_Float16)x; c.h.y = (_Float16)y; return c.u;
}
__device__ __forceinline__ float f16lo(unsigned int u) { U32H2 c; c.u = u; return (float)c.h.x; }
__device__ __forceinline__ float f16hi(unsigned int u) { U32H2 c; c.u = u; return (float)c.h.y; }

// 2-wide f16 dot + fp32 accumulate: v_dot2_f32_f16
__device__ __forceinline__ float dot2u(unsigned int au, unsigned int xu, float acc) {
#if __has_builtin(__builtin_amdgcn_fdot2)
    U32H2 a, x; a.u = au; x.u = xu;
    return __builtin_amdgcn_fdot2(a.h, x.h, acc, false);
#else
    return acc + f16lo(au) * f16lo(xu) + f16hi(au) * f16hi(xu);
#endif
}

// DPP cross-lane (VALU pipe, ~4-8cy vs ds_swizzle ~30-60cy).
template<int CTRL>
__device__ __forceinline__ float dppf(float x) {
    return __uint_as_float((unsigned)__builtin_amdgcn_update_dpp(
        0, (int)__float_as_uint(x), CTRL, 0xF, 0xF, true));
}
__device__ __forceinline__ float red16_max(float x) {
    x = fmaxf(x, dppf<0xB1>(x));    // quad_perm xor1
    x = fmaxf(x, dppf<0x4E>(x));    // quad_perm xor2
    x = fmaxf(x, dppf<0x124>(x));   // row_ror:4
    x = fmaxf(x, dppf<0x128>(x));   // row_ror:8
    return x;
}
__device__ __forceinline__ float red16_sum(float x) {
    x += dppf<0xB1>(x);
    x += dppf<0x4E>(x);
    x += dppf<0x124>(x);
    x += dppf<0x128>(x);
    return x;
}

// Fused prep (one dispatch instead of two — each launch costs ~10-15us bench):
// t < P:        row_ptr boundary scatter (seg sorted)
// t < total25:  hidden fp32 -> packed f16 rows (padded to ROWU uints)
__global__ void prep_kernel(const int* __restrict__ seg,
                            int* __restrict__ row_ptr,
                            const float* __restrict__ hidden,
                            unsigned int* __restrict__ hb,
                            int n, int P, int total25)
{
    int t = blockIdx.x * blockDim.x + threadIdx.x;
    if (t < P) {
        int s0 = seg[t];
        if (t == 0)
            for (int v = 0; v <= s0; v++) row_ptr[v] = 0;
        int s1 = (t + 1 < P) ? seg[t + 1] : n;
        for (int v = s0 + 1; v <= s1; v++) row_ptr[v] = t + 1;
    }
    if (t < total25) {
        int node = t / 25, k = t - node * 25;   // 25 float4-groups per row
        float4 f = ((const float4*)hidden)[t];
        *(uint2*)&hb[node * ROWU + 2 * k] =
            make_uint2(pkh2(f.x, f.y), pkh2(f.z, f.w));
    }
}

// One wave per node. CHUNK=16, 4 lanes/pair, f16 gathers + v_dot2_f32_f16,
// DPP softmax trees, hw in registers. R15: launch_bounds (256,8) — R14's
// VGPR_Count=28 leaves 2x margin under the 64 cap; 32 waves/CU theoretical.
__launch_bounds__(256, 8)
__global__ void gat_agg_kernel(const float* __restrict__ hidden,
                               const float* __restrict__ W,
                               const int* __restrict__ nbr,
                               const int* __restrict__ row_ptr,
                               const unsigned int* __restrict__ hb,
                               float* __restrict__ out,
                               int n)
{
    __shared__ __align__(16) unsigned int s_hwp[4][ROWU];         // 0.83 KB
    __shared__ __align__(16) unsigned int s_rows[4][CHUNK][ROWU]; // 13.3 KB
    __shared__ __align__(16) float        s_e[4][CHUNK];          // 0.25 KB

    const int lane = threadIdx.x & 63;
    const int wid  = threadIdx.x >> 6;
    const int v    = blockIdx.x * 4 + wid;
    if (v >= n) return;          // wave-uniform exit; no block barriers used

    // hw[d] = hidden[v][d] * W[d] (fp32 product, f16-packed into LDS)
    if (lane < 50) {
        float2 h2 = ((const float2*)(hidden + (long)v * D))[lane];
        float2 w2 = ((const float2*)W)[lane];
        s_hwp[wid][lane] = pkh2(h2.x * w2.x, h2.y * w2.y);
    }
    __threadfence_block();

    const int start = row_ptr[v];
    const int end   = row_ptr[v + 1];

    if (end <= start) {          // empty segment: zeros (matches reference)
        if (lane < D / 2)
            ((float2*)(out + (long)v * D))[lane] = make_float2(0.f, 0.f);
        return;
    }

    const int q  = lane >> 4;    // quarter 0..3: uint4s q*3..q*3+2 (+tail on q0)
    const int jl = lane & 15;    // pair slot within the 16-chunk
    const int t0 = q * 3;

    // hoist hw fragment into registers (loop-invariant; 14 regs)
    const uint4* hwq = ((const uint4*)&s_hwp[wid][0]) + t0;
    const uint4 a0 = hwq[0], a1 = hwq[1], a2 = hwq[2];
    uint2 at = make_uint2(0u, 0u);
    if (q == 0) at = *(const uint2*)&s_hwp[wid][48];

    float m = -INFINITY, z = 0.f;
    float accx = 0.f, accy = 0.f;

    for (int c = start; c < end; c += CHUNK) {
        const int  cnt = min(CHUNK, end - c);
        const bool pv  = jl < cnt;

        // invalid lanes gather row 0 (finite, in-bounds); e=0 masks it later
        const int nbv = pv ? nbr[c + jl] : 0;
        const uint4* row16 = ((const uint4*)hb) + nbv * (ROWU / 4) + t0;

        // ---- Phase A: f16 quarter-row gather (3x16B + 8B tail), fdot2 ----
        uint4 x0 = row16[0], x1 = row16[1], x2 = row16[2];
        uint2 xt = make_uint2(0u, 0u);
        if (q == 0) xt = *(const uint2*)&hb[nbv * ROWU + 48];   // dims 96..99

        float p0 = 0.f, p1 = 0.f, p2 = 0.f, p3 = 0.f;
        p0 = dot2u(a0.x, x0.x, p0);  p1 = dot2u(a0.y, x0.y, p1);
        p2 = dot2u(a0.z, x0.z, p2);  p3 = dot2u(a0.w, x0.w, p3);
        p0 = dot2u(a1.x, x1.x, p0);  p1 = dot2u(a1.y, x1.y, p1);
        p2 = dot2u(a1.z, x1.z, p2);  p3 = dot2u(a1.w, x1.w, p3);
        p0 = dot2u(a2.x, x2.x, p0);  p1 = dot2u(a2.y, x2.y, p1);
        p2 = dot2u(a2.z, x2.z, p2);  p3 = dot2u(a2.w, x2.w, p3);
        if (q == 0) {
            p0 = dot2u(at.x, xt.x, p0);
            p1 = dot2u(at.y, xt.y, p1);
        }

        // stage raw f16 row to LDS (16B-aligned: ROWU*4 = 208 = 13*16)
        uint4* dst16 = ((uint4*)&s_rows[wid][jl][0]) + t0;
        dst16[0] = x0; dst16[1] = x1; dst16[2] = x2;
        if (q == 0) *(uint2*)&s_rows[wid][jl][48] = xt;

        float part = (p0 + p1) + (p2 + p3);
        part += __shfl_xor(part, 16, 64);    // combine quarters (LDS pipe)
        part += __shfl_xor(part, 32, 64);
        const float s = pv ? (part >= 0.f ? part : NEG_SLOPE * part)
                           : -INFINITY;

        // ---- online softmax: DPP trees within each 16-group ----
        const float m_new = fmaxf(m, red16_max(s));
        const float scale = __expf(m - m_new);         // first chunk: 0
        const float e     = pv ? __expf(s - m_new) : 0.f;
        z = z * scale + red16_sum(e);
        accx *= scale; accy *= scale;

        if (lane < CHUNK) s_e[wid][lane] = e;          // q0 lanes: jl == lane
        __threadfence_block();                         // LDS stores -> reads

        // ---- Phase B: lane-per-dim accumulate from f16 LDS ----
        const int cnt4 = (cnt + 3) & ~3;               // <= 16
        if (lane < D / 2) {
            for (int j0 = 0; j0 < cnt4; j0 += 4) {
                const float4 ev = *(const float4*)&s_e[wid][j0];  // broadcast
                const unsigned int u0 = s_rows[wid][j0    ][lane];
                const unsigned int u1 = s_rows[wid][j0 + 1][lane];
                const unsigned int u2 = s_rows[wid][j0 + 2][lane];
                const unsigned int u3 = s_rows[wid][j0 + 3][lane];
                accx += ev.x * f16lo(u0);  accy += ev.x * f16hi(u0);
                accx += ev.y * f16lo(u1);  accy += ev.y * f16hi(u1);
                accx += ev.z * f16lo(u2);  accy += ev.z * f16hi(u2);
                accx += ev.w * f16lo(u3);  accy += ev.w * f16hi(u3);
            }
        }
        __threadfence_block();   // phase-B reads done before next chunk's stores
        m = m_new;
    }

    if (lane < D / 2) {
        const float inv = 1.f / z;
        ((float2*)(out + (long)v * D))[lane] = make_float2(accx * inv, accy * inv);
    }
}

extern "C" void kernel_launch(void* const* d_in, const int* in_sizes, int n_in,
                              void* d_out, int out_size, void* d_ws, size_t ws_size,
                              hipStream_t stream) {
    const float* hidden = (const float*)d_in[0];
    const float* W      = (const float*)d_in[1];
    const int*   seg    = (const int*)d_in[2];
    const int*   nbr    = (const int*)d_in[3];
    float*       out    = (float*)d_out;

    const int Ddim = in_sizes[1];           // 100
    const int n    = in_sizes[0] / Ddim;    // 50000
    const int P    = in_sizes[2];           // ~1.3M pairs

    // ws layout: row_ptr (n+1 ints) | hb (n*ROWU uints, 256B-aligned)
    int* row_ptr = (int*)d_ws;
    size_t hb_off = (((size_t)(n + 1) * 4) + 255) & ~(size_t)255;
    unsigned int* hb = (unsigned int*)((char*)d_ws + hb_off);

    const int total25 = n * 25;             // float4-groups in hidden
    const int tmax    = (P > total25) ? P : total25;
    hipLaunchKernelGGL(prep_kernel, dim3((tmax + 255) / 256), dim3(256), 0, stream,
                       seg, row_ptr, hidden, hb, n, P, total25);
    hipLaunchKernelGGL(gat_agg_kernel, dim3((n + 3) / 4), dim3(256), 0, stream,
                       hidden, W, nbr, row_ptr, hb, out, n);
}